// Round 1
// baseline (258.397 us; speedup 1.0000x reference)
//
#include <hip/hip_runtime.h>

// TTRCell: causal linear attention.
//   w_t = w_{t-1} + k_t v_t^T ; out_t = (q_t . w_t) / (t+1)
// Chunked: out_c = [tril(Q_c K_c^T) | Q_c] @ [V_c ; W_c],  W_c = excl-prefix(K^T V per chunk)
// Shapes: q,k (64,4096,64) f32; v (64,4096,64) f32; out (64,4096,64) f32.

#define BH    64
#define SEQ   4096
#define FD    64
#define VD    64
#define CHUNK 64
#define NCH   (SEQ / CHUNK)   // 64

typedef __attribute__((ext_vector_type(8))) short  short8;
typedef __attribute__((ext_vector_type(4))) float  f32x4;

static __device__ __forceinline__ unsigned short f2bf(float f) {
    unsigned int u = __builtin_bit_cast(unsigned int, f);
    u += 0x7FFF + ((u >> 16) & 1);            // round-to-nearest-even
    return (unsigned short)(u >> 16);
}
static __device__ __forceinline__ float bf2f(unsigned short h) {
    unsigned int u = ((unsigned int)h) << 16;
    return __builtin_bit_cast(float, u);
}

// ---------------------------------------------------------------------------
// Pass 1: per chunk, ST[b][ci][v][f] = sum_s V[s][v] * K[s][f]   (= (K^T V)^T)
// Computed as V^T @ K so the f32 global write is coalesced along f.
// grid: BH*NCH blocks of 256 threads.
// ---------------------------------------------------------------------------
__global__ __launch_bounds__(256) void ttr_pass1(const float* __restrict__ k,
                                                 const float* __restrict__ v,
                                                 unsigned short* __restrict__ ST) {
    const int b  = blockIdx.x >> 6;
    const int ci = blockIdx.x & 63;
    __shared__ unsigned short KT[64][72];   // KT[f][s], stride 72 (144B, 16B-aligned)
    __shared__ unsigned short VT[64][72];   // VT[v][s]
    const int tid = threadIdx.x;
    const float* kc = k + ((size_t)b * SEQ + (size_t)ci * CHUNK) * FD;
    const float* vc = v + ((size_t)b * SEQ + (size_t)ci * CHUNK) * FD;

    #pragma unroll
    for (int i = tid; i < 64 * 16; i += 256) {      // 64 rows x 16 float4
        const int s = i >> 4, f4 = (i & 15) << 2;
        float4 kv = *(const float4*)(kc + s * FD + f4);
        float4 vv = *(const float4*)(vc + s * FD + f4);
        KT[f4 + 0][s] = f2bf(kv.x); KT[f4 + 1][s] = f2bf(kv.y);
        KT[f4 + 2][s] = f2bf(kv.z); KT[f4 + 3][s] = f2bf(kv.w);
        VT[f4 + 0][s] = f2bf(vv.x); VT[f4 + 1][s] = f2bf(vv.y);
        VT[f4 + 2][s] = f2bf(vv.z); VT[f4 + 3][s] = f2bf(vv.w);
    }
    __syncthreads();

    const int wid  = tid >> 6;        // wave 0..3 owns v-rows 16w..16w+15
    const int lane = tid & 63;
    const int mrow = lane & 15;       // A-row / B-col selector
    const int kb   = (lane >> 4) << 3;

    f32x4 acc[4] = {};
    #pragma unroll
    for (int ks = 0; ks < 2; ks++) {
        short8 a = *(const short8*)&VT[16 * wid + mrow][ks * 32 + kb];
        #pragma unroll
        for (int cf = 0; cf < 4; cf++) {
            short8 bb = *(const short8*)&KT[16 * cf + mrow][ks * 32 + kb];
            acc[cf] = __builtin_amdgcn_mfma_f32_16x16x32_bf16(a, bb, acc[cf], 0, 0, 0);
        }
    }
    // C layout: col = lane&15 (f), row = (lane>>4)*4 + reg (v within 16)
    unsigned short* outp = ST + (size_t)(b * NCH + ci) * (VD * FD);
    const int vrow0 = 16 * wid + ((lane >> 4) << 2);
    const int fcol  = lane & 15;
    #pragma unroll
    for (int cf = 0; cf < 4; cf++)
        #pragma unroll
        for (int r = 0; r < 4; r++)
            outp[(size_t)(vrow0 + r) * FD + cf * 16 + fcol] = f2bf(acc[cf][r]);
}

// ---------------------------------------------------------------------------
// Pass 2: in-place exclusive prefix over chunks (per head, per element).
// After this, ST holds WT[b][ci][v][f] = sum_{cj<ci} S_cj^T, bf16.
// grid: BH * (4096/256) = 1024 blocks.
// ---------------------------------------------------------------------------
__global__ __launch_bounds__(256) void ttr_pass2(unsigned short* __restrict__ ST) {
    const int b = blockIdx.x >> 4;
    const int e = ((blockIdx.x & 15) << 8) + threadIdx.x;   // 0..4095 element id
    unsigned short* p = ST + (size_t)b * NCH * (VD * FD) + e;
    float acc = 0.f;
    #pragma unroll 8
    for (int ci = 0; ci < NCH; ci++) {
        unsigned short s = p[(size_t)ci * (VD * FD)];
        p[(size_t)ci * (VD * FD)] = f2bf(acc);   // exclusive: write before add
        acc += bf2f(s);
    }
}

// ---------------------------------------------------------------------------
// Pass 3: per chunk, O = (tril(Q K^T) V + Q W) / (t+1)
// Unified as [P | Q](64x128) @ [VT ; WT](128-k x 64), 4 MFMA k-steps.
// grid: BH*NCH blocks of 256 threads (4 waves x 16 rows).
// ---------------------------------------------------------------------------
__global__ __launch_bounds__(256) void ttr_pass3(const float* __restrict__ q,
                                                 const float* __restrict__ k,
                                                 const float* __restrict__ v,
                                                 const unsigned short* __restrict__ WT,
                                                 float* __restrict__ out) {
    const int b  = blockIdx.x >> 6;
    const int ci = blockIdx.x & 63;
    __shared__ unsigned short Qs[64][72];     // Q[t][f] row-major
    __shared__ unsigned short Ks[64][72];     // K[s][f] row-major (B of GEMM1: K^T cancels)
    __shared__ unsigned short VTs[64][136];   // [v][0..63]=V^T ; [v][64+f]=W^T[v][f]=W[f][v]
    __shared__ unsigned short Ps[4][16][72];  // per-wave P slab (16 rows x 64 cols, bf16)
    const int tid = threadIdx.x;
    const float* qc = q + ((size_t)b * SEQ + (size_t)ci * CHUNK) * FD;
    const float* kc = k + ((size_t)b * SEQ + (size_t)ci * CHUNK) * FD;
    const float* vc = v + ((size_t)b * SEQ + (size_t)ci * CHUNK) * FD;

    #pragma unroll
    for (int i = tid; i < 64 * 16; i += 256) {
        const int t = i >> 4, f4 = (i & 15) << 2;
        float4 qv = *(const float4*)(qc + t * FD + f4);
        float4 kv = *(const float4*)(kc + t * FD + f4);
        float4 vv = *(const float4*)(vc + t * FD + f4);
        Qs[t][f4 + 0] = f2bf(qv.x); Qs[t][f4 + 1] = f2bf(qv.y);
        Qs[t][f4 + 2] = f2bf(qv.z); Qs[t][f4 + 3] = f2bf(qv.w);
        Ks[t][f4 + 0] = f2bf(kv.x); Ks[t][f4 + 1] = f2bf(kv.y);
        Ks[t][f4 + 2] = f2bf(kv.z); Ks[t][f4 + 3] = f2bf(kv.w);
        VTs[f4 + 0][t] = f2bf(vv.x); VTs[f4 + 1][t] = f2bf(vv.y);   // transpose V
        VTs[f4 + 2][t] = f2bf(vv.z); VTs[f4 + 3][t] = f2bf(vv.w);
    }
    // stage WT (bf16, already transposed) into VTs[v][64+f] — 16B vector copies
    const unsigned short* wsrc = WT + (size_t)(b * NCH + ci) * (VD * FD);
    #pragma unroll
    for (int i = tid; i < 512; i += 256) {
        const int vv = i >> 3, f8 = (i & 7) << 3;
        *(uint4*)&VTs[vv][64 + f8] = *(const uint4*)(wsrc + vv * FD + f8);
    }
    __syncthreads();

    const int wid  = tid >> 6;
    const int lane = tid & 63;
    const int mrow = lane & 15;
    const int kb   = (lane >> 4) << 3;

    // GEMM1: P(16x64 per wave) = Q K^T, k-dim = f (64)
    f32x4 pacc[4] = {};
    #pragma unroll
    for (int ks = 0; ks < 2; ks++) {
        short8 a = *(const short8*)&Qs[16 * wid + mrow][ks * 32 + kb];
        #pragma unroll
        for (int cf = 0; cf < 4; cf++) {
            short8 bb = *(const short8*)&Ks[16 * cf + mrow][ks * 32 + kb];
            pacc[cf] = __builtin_amdgcn_mfma_f32_16x16x32_bf16(a, bb, pacc[cf], 0, 0, 0);
        }
    }
    // causal mask (col <= row, diagonal inclusive) + convert to bf16 slab
    const int prow0 = (lane >> 4) << 2;
    const int pcol  = lane & 15;
    #pragma unroll
    for (int cf = 0; cf < 4; cf++)
        #pragma unroll
        for (int r = 0; r < 4; r++) {
            const int row_local = 16 * wid + prow0 + r;
            const int col       = cf * 16 + pcol;
            const float val = (col <= row_local) ? pacc[cf][r] : 0.f;
            Ps[wid][prow0 + r][cf * 16 + pcol] = f2bf(val);
        }
    __syncthreads();   // orders the wave-local LDS write->read (conservative)

    // GEMM2: O(16x64 per wave) = [P | Q] @ [V^T ; W^T-as-B], k-dim = 128
    f32x4 oacc[4] = {};
    #pragma unroll
    for (int ks = 0; ks < 4; ks++) {
        short8 a;
        if (ks < 2) a = *(const short8*)&Ps[wid][mrow][ks * 32 + kb];
        else        a = *(const short8*)&Qs[16 * wid + mrow][(ks - 2) * 32 + kb];
        #pragma unroll
        for (int cn = 0; cn < 4; cn++) {
            short8 bb = *(const short8*)&VTs[16 * cn + mrow][ks * 32 + kb];
            oacc[cn] = __builtin_amdgcn_mfma_f32_16x16x32_bf16(a, bb, oacc[cn], 0, 0, 0);
        }
    }
    // epilogue: divide by (t_global + 1), store f32 coalesced per 16-lane group
    float* oc = out + ((size_t)b * SEQ + (size_t)ci * CHUNK) * VD;
    #pragma unroll
    for (int cn = 0; cn < 4; cn++)
        #pragma unroll
        for (int r = 0; r < 4; r++) {
            const int row_local = 16 * wid + prow0 + r;
            const float den = (float)(ci * CHUNK + row_local + 1);
            oc[(size_t)row_local * VD + cn * 16 + pcol] = oacc[cn][r] / den;
        }
}

// ---------------------------------------------------------------------------
extern "C" void kernel_launch(void* const* d_in, const int* in_sizes, int n_in,
                              void* d_out, int out_size, void* d_ws, size_t ws_size,
                              hipStream_t stream) {
    const float* q = (const float*)d_in[0];
    const float* k = (const float*)d_in[1];
    const float* v = (const float*)d_in[2];
    float* out = (float*)d_out;
    // workspace: BH*NCH*VD*FD bf16 = 33.55 MB (chunk KV sums -> in-place prefix -> W^T)
    unsigned short* ST = (unsigned short*)d_ws;

    ttr_pass1<<<BH * NCH, 256, 0, stream>>>(k, v, ST);
    ttr_pass2<<<BH * (SEQ / CHUNK / 4), 256, 0, stream>>>(ST);  // 64*16 = 1024 blocks
    ttr_pass3<<<BH * NCH, 256, 0, stream>>>(q, k, v, ST, out);
}